// Round 4
// baseline (52.576 us; speedup 1.0000x reference)
//
#include <hip/hip_runtime.h>
#include <math.h>

// Problem constants (match setup_inputs)
#define B_ 4
#define N_ 128
#define D_ 160
#define H_ 192
#define W_ 160

// Native clang vector type (required by __builtin_nontemporal_store;
// HIP's float4 is a class and is rejected).
typedef float floatx4 __attribute__((ext_vector_type(4)));

// ---------------------------------------------------------------------------
// Kernel 1: weighted Kabsch rigid transform.
// ONE block, 256 threads: wave b (of 4) handles batch b, each lane 2 points.
// All reductions are wave-local __shfl_xor butterflies (no barriers).
// Polar decomposition: det-scaled Newton X <- 0.5*(mu*X + C/(mu*det)),
// 9 iters, f64 iterates, fp32 mu (mu precision only affects convergence
// SPEED, not the fixed point) -- avoids serial f64 pow() calls.
//
// Reference math: p1 = points_f, p2 = points_m, w normalized.
//   c1 = sum w*p1 ; c2 = sum w*p2
//   H[i][j] = sum_n w^2 (p1_i - c1_i)(p2_j - c2_j)
//   R_init = V U^T = Q^T (Q = orthogonal polar factor of H)
//   R = diag(1,1,sign(det(R_init))) * R_init   (ref scales 3rd ROW of V)
//   T = c2 - R c1
// ---------------------------------------------------------------------------
__global__ __launch_bounds__(256) void rigid_kernel(const float* __restrict__ pm,
                                                    const float* __restrict__ pf,
                                                    const float* __restrict__ wt,
                                                    float* __restrict__ theta) {
  __shared__ float bc[B_][15]; // per batch: c1(3), c2(3), H(9)
  const int tid = threadIdx.x;
  const int b = tid >> 6;     // wave index = batch
  const int lane = tid & 63;

  // two points per lane: n = lane, lane+64
  const int base = b * N_;
  float wA = wt[base + lane], wB = wt[base + lane + 64];
  float fA[3], fB[3], mA[3], mB[3];
#pragma unroll
  for (int c = 0; c < 3; ++c) {
    fA[c] = pf[(base + lane) * 3 + c];
    fB[c] = pf[(base + lane + 64) * 3 + c];
    mA[c] = pm[(base + lane) * 3 + c];
    mB[c] = pm[(base + lane + 64) * 3 + c];
  }

  // --- centroids: 6 wave butterfly reductions (no barriers) ---
  float sums[6];
#pragma unroll
  for (int c = 0; c < 3; ++c) {
    sums[c]     = wA * fA[c] + wB * fB[c];
    sums[3 + c] = wA * mA[c] + wB * mB[c];
  }
#pragma unroll
  for (int k = 0; k < 6; ++k) {
    float v = sums[k];
#pragma unroll
    for (int o = 1; o < 64; o <<= 1) v += __shfl_xor(v, o, 64);
    sums[k] = v;
  }

  // --- cross-covariance H: 9 butterfly reductions ---
  float q1A[3], q1B[3], q2A[3], q2B[3];
#pragma unroll
  for (int c = 0; c < 3; ++c) {
    q1A[c] = (fA[c] - sums[c]) * wA;     q1B[c] = (fB[c] - sums[c]) * wB;
    q2A[c] = (mA[c] - sums[3 + c]) * wA; q2B[c] = (mB[c] - sums[3 + c]) * wB;
  }
  float Hm[9];
#pragma unroll
  for (int i = 0; i < 3; ++i)
#pragma unroll
    for (int j = 0; j < 3; ++j)
      Hm[i * 3 + j] = q1A[i] * q2A[j] + q1B[i] * q2B[j];
#pragma unroll
  for (int k = 0; k < 9; ++k) {
    float v = Hm[k];
#pragma unroll
    for (int o = 1; o < 64; o <<= 1) v += __shfl_xor(v, o, 64);
    Hm[k] = v;
  }

  if (lane == 0) {
#pragma unroll
    for (int k = 0; k < 6; ++k) bc[b][k] = sums[k];
#pragma unroll
    for (int k = 0; k < 9; ++k) bc[b][6 + k] = Hm[k];
  }
  __syncthreads();

  // --- polar solve: lanes 0..3 of wave 0, SIMD-parallel over batches ---
  if (tid < B_) {
    const int bb = tid;
    double X[3][3];
    double fr = 0.0;
    for (int i = 0; i < 3; ++i)
      for (int j = 0; j < 3; ++j) {
        X[i][j] = (double)bc[bb][6 + i * 3 + j];
        fr += X[i][j] * X[i][j];
      }
    fr = sqrt(fr);
    if (fr < 1e-300) fr = 1.0;
    for (int i = 0; i < 3; ++i)
      for (int j = 0; j < 3; ++j) X[i][j] /= fr;

    for (int it = 0; it < 9; ++it) {
      double C[3][3];
      C[0][0] =  X[1][1] * X[2][2] - X[1][2] * X[2][1];
      C[0][1] = -(X[1][0] * X[2][2] - X[1][2] * X[2][0]);
      C[0][2] =  X[1][0] * X[2][1] - X[1][1] * X[2][0];
      C[1][0] = -(X[0][1] * X[2][2] - X[0][2] * X[2][1]);
      C[1][1] =  X[0][0] * X[2][2] - X[0][2] * X[2][0];
      C[1][2] = -(X[0][0] * X[2][1] - X[0][1] * X[2][0]);
      C[2][0] =  X[0][1] * X[1][2] - X[0][2] * X[1][1];
      C[2][1] = -(X[0][0] * X[1][2] - X[0][2] * X[1][0]);
      C[2][2] =  X[0][0] * X[1][1] - X[0][1] * X[1][0];
      double det = X[0][0] * C[0][0] + X[0][1] * C[0][1] + X[0][2] * C[0][2];
      // accelerated Newton: mu ~= |det|^(-1/3); fp32 precision is plenty
      // (mu only affects convergence rate, not the fixed point).
      float adf = fabsf((float)det);
      float muf = (adf > 1e-30f && adf < 1e30f)
                      ? exp2f(log2f(adf) * (-1.0f / 3.0f)) : 1.0f;
      double mu = (double)muf;
      double inv = 1.0 / (mu * det);
      for (int i = 0; i < 3; ++i)
        for (int j = 0; j < 3; ++j)
          X[i][j] = 0.5 * (mu * X[i][j] + C[i][j] * inv);
    }

    // R_init = X^T (= V U^T)
    double R[3][3];
    for (int i = 0; i < 3; ++i)
      for (int j = 0; j < 3; ++j) R[i][j] = X[j][i];

    double det = R[0][0] * (R[1][1] * R[2][2] - R[1][2] * R[2][1])
               - R[0][1] * (R[1][0] * R[2][2] - R[1][2] * R[2][0])
               + R[0][2] * (R[1][0] * R[2][1] - R[1][1] * R[2][0]);
    double s = (det < 0.0) ? -1.0 : 1.0;
    R[2][0] *= s; R[2][1] *= s; R[2][2] *= s;

    const double c1d[3] = {bc[bb][0], bc[bb][1], bc[bb][2]};
    const double c2d[3] = {bc[bb][3], bc[bb][4], bc[bb][5]};
    for (int i = 0; i < 3; ++i) {
      double Ti = c2d[i] - (R[i][0] * c1d[0] + R[i][1] * c1d[1] + R[i][2] * c1d[2]);
      theta[bb * 12 + i * 4 + 0] = (float)R[i][0];
      theta[bb * 12 + i * 4 + 1] = (float)R[i][1];
      theta[bb * 12 + i * 4 + 2] = (float)R[i][2];
      theta[bb * 12 + i * 4 + 3] = (float)Ti;
    }
  }
}

// ---------------------------------------------------------------------------
// Kernel 2: affine grid generation. Write-streaming (236 MB out).
// out[b,d,h,w,i] = theta[b,i,0]*x + theta[b,i,1]*y + theta[b,i,2]*z + theta[b,i,3]
//   x = (2w+1)/W - 1, y = (2h+1)/H - 1, z = (2d+1)/D - 1
//
// One thread = 8 output float4s at stride 256 within the block's 2048-f4
// span: every store instruction is still 64 lanes x 16 B = 1 KiB contiguous,
// but block count drops 57600 -> 7200 (wave-dispatch overhead /8, 8 KB/wave).
// 2048 | per-batch f4 count (3,686,400 = 1800*2048) so b is BLOCK-UNIFORM:
// theta loads become scalar loads hoisted out of the k-loop.
// Nontemporal stores: pure streaming, zero reuse -> evict-first.
// ---------------------------------------------------------------------------
#define F_PER_ROW ((W_ * 3) / 4)              /* 120 float4s per row */
#define F4_TOTAL (B_ * D_ * H_ * F_PER_ROW)   /* 14,745,600 */
#define BLOCKS_PER_BATCH 1800                 /* (F4_TOTAL/B_)/2048 exact */

__global__ __launch_bounds__(256) void grid_kernel(const float* __restrict__ theta,
                                                   floatx4* __restrict__ out) {
  const int tid = threadIdx.x;
  const int blk = blockIdx.x;
  const int b = blk / BLOCKS_PER_BATCH; // block-uniform -> scalar

  const float* th = theta + b * 12;
  const float r00 = th[0], r01 = th[1], r02 = th[2],  t0 = th[3];
  const float r10 = th[4], r11 = th[5], r12 = th[6],  t1 = th[7];
  const float r20 = th[8], r21 = th[9], r22 = th[10], t2 = th[11];
  const float dx = 2.0f / (float)W_;

  int f = blk * 2048 + tid;
#pragma unroll
  for (int k = 0; k < 8; ++k, f += 256) {
    const int row = f / F_PER_ROW;
    const int lf4 = f - row * F_PER_ROW;
    const int h = row % H_;
    const int d = (row / H_) % D_;

    const int lf = lf4 * 4;        // float offset within row, 0..476
    const int w0 = lf / 3;         // first voxel covered
    const int phase = lf - 3 * w0; // 0,1,2

    const float y = (2.0f * (float)h + 1.0f) * (1.0f / (float)H_) - 1.0f;
    const float z = (2.0f * (float)d + 1.0f) * (1.0f / (float)D_) - 1.0f;
    const float x0 = (2.0f * (float)w0 + 1.0f) * (1.0f / (float)W_) - 1.0f;

    const float A0 = fmaf(r00, x0, fmaf(r01, y, fmaf(r02, z, t0)));
    const float A1 = fmaf(r10, x0, fmaf(r11, y, fmaf(r12, z, t1)));
    const float A2 = fmaf(r20, x0, fmaf(r21, y, fmaf(r22, z, t2)));
    const float B0 = fmaf(r00, dx, A0);
    const float B1 = fmaf(r10, dx, A1);
    const float B2 = fmaf(r20, dx, A2);

    floatx4 o;
    o.x = (phase == 0) ? A0 : ((phase == 1) ? A1 : A2);
    o.y = (phase == 0) ? A1 : ((phase == 1) ? A2 : B0);
    o.z = (phase == 0) ? A2 : ((phase == 1) ? B0 : B1);
    o.w = (phase == 0) ? B0 : ((phase == 1) ? B1 : B2);

    __builtin_nontemporal_store(o, out + f);
  }
}

extern "C" void kernel_launch(void* const* d_in, const int* in_sizes, int n_in,
                              void* d_out, int out_size, void* d_ws, size_t ws_size,
                              hipStream_t stream) {
  const float* pm = (const float*)d_in[0]; // points_m [B,N,3]
  const float* pf = (const float*)d_in[1]; // points_f [B,N,3]
  const float* wt = (const float*)d_in[2]; // weights  [B,1,N]
  float* theta = (float*)d_ws;             // [B,3,4]
  floatx4* out = (floatx4*)d_out;          // [B,D,H,W,3] f32 as float4s

  rigid_kernel<<<1, 256, 0, stream>>>(pm, pf, wt, theta);

  const int nBlocks = F4_TOTAL / 2048; // 7200
  grid_kernel<<<nBlocks, 256, 0, stream>>>(theta, out);
}

// Round 5
// 44.609 us; speedup vs baseline: 1.1786x; 1.1786x over previous
//
#include <hip/hip_runtime.h>
#include <math.h>

// Problem constants (match setup_inputs)
#define B_ 4
#define N_ 128
#define D_ 160
#define H_ 192
#define W_ 160

// Native clang vector type (16B stores; also valid for plain assignment).
typedef float floatx4 __attribute__((ext_vector_type(4)));

// ---------------------------------------------------------------------------
// Kernel 1: weighted Kabsch rigid transform — all fp32.
// ONE block, 256 threads: wave b (of 4) handles batch b, each lane 2 points.
// All reductions are wave-local __shfl_xor butterflies (no barriers).
// Polar decomposition: det-scaled Newton X <- 0.5*(mu*X + C/(mu*det)),
// 8 iters in f32. The fixed point is the exact orthogonal polar factor;
// f32 stalls at ~1e-6 rotation error (threshold is 3.7e-2 -- huge headroom).
//
// Reference math: p1 = points_f, p2 = points_m, w normalized.
//   c1 = sum w*p1 ; c2 = sum w*p2
//   H[i][j] = sum_n w^2 (p1_i - c1_i)(p2_j - c2_j)
//   R_init = V U^T = Q^T (Q = orthogonal polar factor of H)
//   R = diag(1,1,sign(det(R_init))) * R_init   (ref scales 3rd ROW of V)
//   T = c2 - R c1
// ---------------------------------------------------------------------------
__global__ __launch_bounds__(256) void rigid_kernel(const float* __restrict__ pm,
                                                    const float* __restrict__ pf,
                                                    const float* __restrict__ wt,
                                                    float* __restrict__ theta) {
  __shared__ float bc[B_][15]; // per batch: c1(3), c2(3), H(9)
  const int tid = threadIdx.x;
  const int b = tid >> 6;     // wave index = batch
  const int lane = tid & 63;

  // two points per lane: n = lane, lane+64
  const int base = b * N_;
  float wA = wt[base + lane], wB = wt[base + lane + 64];
  float fA[3], fB[3], mA[3], mB[3];
#pragma unroll
  for (int c = 0; c < 3; ++c) {
    fA[c] = pf[(base + lane) * 3 + c];
    fB[c] = pf[(base + lane + 64) * 3 + c];
    mA[c] = pm[(base + lane) * 3 + c];
    mB[c] = pm[(base + lane + 64) * 3 + c];
  }

  // --- centroids: 6 wave butterfly reductions (no barriers) ---
  float sums[6];
#pragma unroll
  for (int c = 0; c < 3; ++c) {
    sums[c]     = wA * fA[c] + wB * fB[c];
    sums[3 + c] = wA * mA[c] + wB * mB[c];
  }
#pragma unroll
  for (int k = 0; k < 6; ++k) {
    float v = sums[k];
#pragma unroll
    for (int o = 1; o < 64; o <<= 1) v += __shfl_xor(v, o, 64);
    sums[k] = v;
  }

  // --- cross-covariance H: 9 butterfly reductions ---
  float q1A[3], q1B[3], q2A[3], q2B[3];
#pragma unroll
  for (int c = 0; c < 3; ++c) {
    q1A[c] = (fA[c] - sums[c]) * wA;     q1B[c] = (fB[c] - sums[c]) * wB;
    q2A[c] = (mA[c] - sums[3 + c]) * wA; q2B[c] = (mB[c] - sums[3 + c]) * wB;
  }
  float Hm[9];
#pragma unroll
  for (int i = 0; i < 3; ++i)
#pragma unroll
    for (int j = 0; j < 3; ++j)
      Hm[i * 3 + j] = q1A[i] * q2A[j] + q1B[i] * q2B[j];
#pragma unroll
  for (int k = 0; k < 9; ++k) {
    float v = Hm[k];
#pragma unroll
    for (int o = 1; o < 64; o <<= 1) v += __shfl_xor(v, o, 64);
    Hm[k] = v;
  }

  if (lane == 0) {
#pragma unroll
    for (int k = 0; k < 6; ++k) bc[b][k] = sums[k];
#pragma unroll
    for (int k = 0; k < 9; ++k) bc[b][6 + k] = Hm[k];
  }
  __syncthreads();

  // --- polar solve: lanes 0..3 of wave 0, SIMD-parallel over batches, f32 ---
  if (tid < B_) {
    const int bb = tid;
    float X[3][3];
    float fr = 0.0f;
#pragma unroll
    for (int i = 0; i < 3; ++i)
#pragma unroll
      for (int j = 0; j < 3; ++j) {
        X[i][j] = bc[bb][6 + i * 3 + j];
        fr = fmaf(X[i][j], X[i][j], fr);
      }
    fr = sqrtf(fr);
    if (fr < 1e-30f) fr = 1.0f;
    const float ifr = 1.0f / fr;
#pragma unroll
    for (int i = 0; i < 3; ++i)
#pragma unroll
      for (int j = 0; j < 3; ++j) X[i][j] *= ifr;

    for (int it = 0; it < 8; ++it) {
      float C[3][3];
      C[0][0] =  X[1][1] * X[2][2] - X[1][2] * X[2][1];
      C[0][1] = -(X[1][0] * X[2][2] - X[1][2] * X[2][0]);
      C[0][2] =  X[1][0] * X[2][1] - X[1][1] * X[2][0];
      C[1][0] = -(X[0][1] * X[2][2] - X[0][2] * X[2][1]);
      C[1][1] =  X[0][0] * X[2][2] - X[0][2] * X[2][0];
      C[1][2] = -(X[0][0] * X[2][1] - X[0][1] * X[2][0]);
      C[2][0] =  X[0][1] * X[1][2] - X[0][2] * X[1][1];
      C[2][1] = -(X[0][0] * X[1][2] - X[0][2] * X[1][0]);
      C[2][2] =  X[0][0] * X[1][1] - X[0][1] * X[1][0];
      float det = X[0][0] * C[0][0] + X[0][1] * C[0][1] + X[0][2] * C[0][2];
      // accelerated Newton: mu ~= |det|^(-1/3); precision only affects
      // convergence rate, not the fixed point.
      float ad = fabsf(det);
      float mu = (ad > 1e-30f && ad < 1e30f)
                     ? exp2f(log2f(ad) * (-1.0f / 3.0f)) : 1.0f;
      float inv = 1.0f / (mu * det);
#pragma unroll
      for (int i = 0; i < 3; ++i)
#pragma unroll
        for (int j = 0; j < 3; ++j)
          X[i][j] = 0.5f * fmaf(mu, X[i][j], C[i][j] * inv);
    }

    // R_init = X^T (= V U^T)
    float R[3][3];
#pragma unroll
    for (int i = 0; i < 3; ++i)
#pragma unroll
      for (int j = 0; j < 3; ++j) R[i][j] = X[j][i];

    float det = R[0][0] * (R[1][1] * R[2][2] - R[1][2] * R[2][1])
              - R[0][1] * (R[1][0] * R[2][2] - R[1][2] * R[2][0])
              + R[0][2] * (R[1][0] * R[2][1] - R[1][1] * R[2][0]);
    float s = (det < 0.0f) ? -1.0f : 1.0f;
    R[2][0] *= s; R[2][1] *= s; R[2][2] *= s;

    const float c1d[3] = {bc[bb][0], bc[bb][1], bc[bb][2]};
    const float c2d[3] = {bc[bb][3], bc[bb][4], bc[bb][5]};
#pragma unroll
    for (int i = 0; i < 3; ++i) {
      float Ti = c2d[i] - (R[i][0] * c1d[0] + R[i][1] * c1d[1] + R[i][2] * c1d[2]);
      theta[bb * 12 + i * 4 + 0] = R[i][0];
      theta[bb * 12 + i * 4 + 1] = R[i][1];
      theta[bb * 12 + i * 4 + 2] = R[i][2];
      theta[bb * 12 + i * 4 + 3] = Ti;
    }
  }
}

// ---------------------------------------------------------------------------
// Kernel 2: affine grid generation. Write-streaming (236 MB out).
// out[b,d,h,w,i] = theta[b,i,0]*x + theta[b,i,1]*y + theta[b,i,2]*z + theta[b,i,3]
//   x = (2w+1)/W - 1, y = (2h+1)/H - 1, z = (2d+1)/D - 1
//
// One thread = 8 output float4s at stride 256 within the block's 2048-f4
// span: every store instruction is 64 lanes x 16 B = 1 KiB contiguous.
// 2048 | per-batch f4 count (3,686,400 = 1800*2048) so b is BLOCK-UNIFORM:
// theta loads are scalar, hoisted out of the k-loop.
// PLAIN stores (R4's nontemporal stores regressed ~5 us: bypassing L2
// write-aggregation hurts; the harness fill kernel proves plain streaming
// stores sustain ~7 TB/s on this buffer).
// ---------------------------------------------------------------------------
#define F_PER_ROW ((W_ * 3) / 4)              /* 120 float4s per row */
#define F4_TOTAL (B_ * D_ * H_ * F_PER_ROW)   /* 14,745,600 */
#define BLOCKS_PER_BATCH 1800                 /* (F4_TOTAL/B_)/2048 exact */

__global__ __launch_bounds__(256) void grid_kernel(const float* __restrict__ theta,
                                                   floatx4* __restrict__ out) {
  const int tid = threadIdx.x;
  const int blk = blockIdx.x;
  const int b = blk / BLOCKS_PER_BATCH; // block-uniform -> scalar

  const float* th = theta + b * 12;
  const float r00 = th[0], r01 = th[1], r02 = th[2],  t0 = th[3];
  const float r10 = th[4], r11 = th[5], r12 = th[6],  t1 = th[7];
  const float r20 = th[8], r21 = th[9], r22 = th[10], t2 = th[11];
  const float dx = 2.0f / (float)W_;

  int f = blk * 2048 + tid;
#pragma unroll
  for (int k = 0; k < 8; ++k, f += 256) {
    const int row = f / F_PER_ROW;
    const int lf4 = f - row * F_PER_ROW;
    const int h = row % H_;
    const int d = (row / H_) % D_;

    const int lf = lf4 * 4;        // float offset within row, 0..476
    const int w0 = lf / 3;         // first voxel covered
    const int phase = lf - 3 * w0; // 0,1,2

    const float y = (2.0f * (float)h + 1.0f) * (1.0f / (float)H_) - 1.0f;
    const float z = (2.0f * (float)d + 1.0f) * (1.0f / (float)D_) - 1.0f;
    const float x0 = (2.0f * (float)w0 + 1.0f) * (1.0f / (float)W_) - 1.0f;

    const float A0 = fmaf(r00, x0, fmaf(r01, y, fmaf(r02, z, t0)));
    const float A1 = fmaf(r10, x0, fmaf(r11, y, fmaf(r12, z, t1)));
    const float A2 = fmaf(r20, x0, fmaf(r21, y, fmaf(r22, z, t2)));
    const float B0 = fmaf(r00, dx, A0);
    const float B1 = fmaf(r10, dx, A1);
    const float B2 = fmaf(r20, dx, A2);

    floatx4 o;
    o.x = (phase == 0) ? A0 : ((phase == 1) ? A1 : A2);
    o.y = (phase == 0) ? A1 : ((phase == 1) ? A2 : B0);
    o.z = (phase == 0) ? A2 : ((phase == 1) ? B0 : B1);
    o.w = (phase == 0) ? B0 : ((phase == 1) ? B1 : B2);

    out[f] = o;
  }
}

extern "C" void kernel_launch(void* const* d_in, const int* in_sizes, int n_in,
                              void* d_out, int out_size, void* d_ws, size_t ws_size,
                              hipStream_t stream) {
  const float* pm = (const float*)d_in[0]; // points_m [B,N,3]
  const float* pf = (const float*)d_in[1]; // points_f [B,N,3]
  const float* wt = (const float*)d_in[2]; // weights  [B,1,N]
  float* theta = (float*)d_ws;             // [B,3,4]
  floatx4* out = (floatx4*)d_out;          // [B,D,H,W,3] f32 as float4s

  rigid_kernel<<<1, 256, 0, stream>>>(pm, pf, wt, theta);

  const int nBlocks = F4_TOTAL / 2048; // 7200
  grid_kernel<<<nBlocks, 256, 0, stream>>>(theta, out);
}